// Round 10
// baseline (1015.200 us; speedup 1.0000x reference)
//
#include <hip/hip_runtime.h>

// WaveNet residual stack, MFMA bf16. 13 dispatches total:
//   prep + per stack { fused6 (d=1..32) + pair<64> (d=64,128) + pair<256> (d=256,512) }.
// Skip GEMM fused INTO the chain kernels (g never leaves LDS; out written
// directly). Stream kept fp32 with a bf16 LDS shadow so MFMA A-fragments are
// direct ds_read_b128. R10 fix: last tile also owns skip rows >=96 (coverage
// hole for blocks j<5 whose Lj > ntiles*96).

#define CC    64
#define SCC   256
#define BB    4
#define LL0   8192
#define NBLK  40
#define SKIPN 4096

typedef __attribute__((ext_vector_type(8))) short bf16x8;
typedef __attribute__((ext_vector_type(4))) float f32x4;
typedef unsigned short us;

__device__ __forceinline__ us f2bf(float f) {
    union { float f; unsigned u; } v; v.f = f;
    return (us)((v.u + 0x7FFF + ((v.u >> 16) & 1)) >> 16);
}
__device__ __forceinline__ unsigned pk2(float a, float b) {
    return (unsigned)f2bf(a) | ((unsigned)f2bf(b) << 16);
}
__device__ __forceinline__ uint2 pk4(f32x4 v) {
    return (uint2){pk2(v[0], v[1]), pk2(v[2], v[3])};
}
// fp32 [row][64] LDS word index, 32B-chunk XOR swizzle
__device__ __forceinline__ int sws(int r, int c) {
    return (r << 6) + ((((c >> 3) ^ r) & 7) << 3) + (c & 7);
}
// bf16 [row][64] LDS elem index, 16B-chunk XOR swizzle
__device__ __forceinline__ int swh(int r, int c) {
    return (r << 6) + ((((c >> 3) ^ r) & 7) << 3) + (c & 7);
}
// wave-private bf16 scratch [16 rows][64 c], 16B-chunk XOR swizzle
__device__ __forceinline__ int scb(int s, int chunk) {
    return (s << 6) + (((chunk ^ (s & 7)) & 7) << 3);
}

// ---- merged prep: x transpose [b][c][t]->[b][t][c] + weight bf16 casts ----
__global__ __launch_bounds__(256) void prep_kernel(
    const float* __restrict__ x, float* __restrict__ xt_out,
    const float* __restrict__ dc_w, const float* __restrict__ conv_w,
    const float* __restrict__ skip_w,
    us* __restrict__ wcat, us* __restrict__ cwb, us* __restrict__ swb)
{
    if (blockIdx.x < 512) {
        __shared__ float tile[64][65];
        const int b = blockIdx.x >> 7, t0 = (blockIdx.x & 127) * 64;
        const int tid = threadIdx.x;
        #pragma unroll
        for (int p = 0; p < 4; ++p) {
            const int c = p * 16 + (tid >> 4), j = tid & 15;
            const float4 v = *(const float4*)(x + ((size_t)b * CC + c) * LL0 + t0 + j * 4);
            tile[c][j*4+0]=v.x; tile[c][j*4+1]=v.y; tile[c][j*4+2]=v.z; tile[c][j*4+3]=v.w;
        }
        __syncthreads();
        #pragma unroll
        for (int p = 0; p < 4; ++p) {
            const int r = p * 16 + (tid >> 4), h = tid & 15;
            float4 v = {tile[h*4+0][r], tile[h*4+1][r], tile[h*4+2][r], tile[h*4+3][r]};
            *(float4*)(xt_out + ((size_t)b * LL0 + t0 + r) * CC + h * 4) = v;
        }
        return;
    }
    const int n_sw = NBLK * SCC * CC, n_cw = NBLK * CC * CC, n_wc = NBLK * CC * 128;
    for (int idx = (blockIdx.x - 512) * blockDim.x + threadIdx.x; idx < n_sw;
         idx += 1024 * blockDim.x) {
        swb[idx] = f2bf(skip_w[idx]);
        if (idx < n_cw) cwb[idx] = f2bf(conv_w[idx]);
        if (idx < n_wc) {
            const int i = idx >> 13, o = (idx >> 7) & 63, kk = idx & 127;
            wcat[idx] = f2bf(dc_w[(((i * CC + o) * CC) + (kk & 63)) * 2 + (kk >> 6)]);
        }
    }
}

// ---- in-chain skip GEMM for one 16-row t-group the wave owns ----
__device__ __forceinline__ void skip16(
    bf16x8 g0, bf16x8 g1,
    const us* __restrict__ sw, const float* __restrict__ sb,
    float* __restrict__ op, int tbase, int wb, int Lend,
    int s, int q, int nlo, int nhi)
{
    if (tbase + 15 < wb || tbase >= Lend) return;
    const int t4 = tbase + q * 4;
    const bool fullvec = (t4 >= wb) && (t4 + 3 < Lend);
    #pragma unroll 4
    for (int n = nlo; n < nhi; ++n) {
        const int sc = n * 16 + s;
        const float bias = sb[sc];
        f32x4 acc = (f32x4){bias, bias, bias, bias};
        const us* wr = sw + sc * CC + q * 8;
        acc = __builtin_amdgcn_mfma_f32_16x16x32_bf16(g0, *(const bf16x8*)(wr),      acc, 0, 0, 0);
        acc = __builtin_amdgcn_mfma_f32_16x16x32_bf16(g1, *(const bf16x8*)(wr + 32), acc, 0, 0, 0);
        if (fullvec) {
            *(float4*)(op + (size_t)sc * SKIPN + (t4 - wb)) =
                (float4){acc[0], acc[1], acc[2], acc[3]};
        } else {
            #pragma unroll
            for (int r = 0; r < 4; ++r)
                if (t4 + r >= wb && t4 + r < Lend)
                    op[(size_t)sc * SKIPN + (t4 + r - wb)] = acc[r];
        }
    }
}

// ================= fused d=1..32 kernel (512 threads) =================
__global__ __launch_bounds__(512) void fused6_kernel(
    const float* __restrict__ cur, float* __restrict__ nxt,
    const us* __restrict__ wcat_all, const us* __restrict__ cwb_all,
    const float* __restrict__ db_all, const float* __restrict__ cb_all,
    const us* __restrict__ swb_all, const float* __restrict__ sb_all,
    float* __restrict__ out_all, int blk0, int Lin, int ntiles)
{
    constexpr int TOUT = 96, R0 = 159, RCAP = 160;
    __shared__ __align__(16) float sm[RCAP * CC];
    __shared__ __align__(16) us  smb[RCAP * CC];
    __shared__ __align__(16) us  scr[8 * 16 * CC];

    const int tid = threadIdx.x, lane = tid & 63, wv = tid >> 6;
    const int b = blockIdx.x / ntiles, tix = blockIdx.x % ntiles;
    const int t0 = tix * TOUT;
    const bool lastt = (tix == ntiles - 1);
    const float* src = cur + (size_t)b * LL0 * CC;
    const int s = lane & 15, q = lane >> 4;
    us* myscr = scr + wv * (16 * CC);

    // stage R0 stream rows: fp32 + bf16 shadow
    for (int base = 0; base < R0; base += 32) {
        const int row = base + (tid >> 4);
        const int h4 = (tid & 15) * 4;
        if (row < R0) {
            int gt = t0 + row; if (gt > Lin - 1) gt = Lin - 1;
            f32x4 v = *(const f32x4*)(src + (size_t)gt * CC + h4);
            *(f32x4*)(sm + sws(row, h4)) = v;
            *(uint2*)(smb + swh(row, h4)) = pk4(v);
        }
    }
    __syncthreads();

    int Rcur = R0, Lj = Lin;
    for (int j = 0; j < 6; ++j) {
        const int d = 1 << j;
        const int Rn = Rcur - d;
        Lj -= d;
        const us* wj = wcat_all + (size_t)(blk0 + j) * CC * 128;
        const us* cj = cwb_all + (size_t)(blk0 + j) * CC * CC;
        const us* sj = swb_all + (size_t)(blk0 + j) * SCC * CC;
        const float* dbj = db_all + (blk0 + j) * CC;
        const float* cbj = cb_all + (blk0 + j) * CC;
        const float* sbj = sb_all + (blk0 + j) * SCC;
        float* opj = out_all + ((size_t)(blk0 + j) * BB + b) * SCC * SKIPN;

        f32x4 r2[2][4];
        #pragma unroll
        for (int fi = 0; fi < 2; ++fi) {
            const int fg = wv + fi * 8;
            if (fg * 16 < Rn) {
                const int t = fg * 16 + s;
                const int tc = t > Rn - 1 ? Rn - 1 : t;
                bf16x8 af0 = *(const bf16x8*)(smb + swh(tc,     q * 8));
                bf16x8 af1 = *(const bf16x8*)(smb + swh(tc,     32 + q * 8));
                bf16x8 af2 = *(const bf16x8*)(smb + swh(tc + d, q * 8));
                bf16x8 af3 = *(const bf16x8*)(smb + swh(tc + d, 32 + q * 8));
                #pragma unroll
                for (int n = 0; n < 4; ++n) {
                    const int o0 = n * 16 + q * 4;
                    f32x4 acc = *(const f32x4*)(dbj + o0);
                    const us* wr = wj + (n * 16 + s) * 128 + q * 8;
                    acc = __builtin_amdgcn_mfma_f32_16x16x32_bf16(*(const bf16x8*)(wr),      af0, acc, 0, 0, 0);
                    acc = __builtin_amdgcn_mfma_f32_16x16x32_bf16(*(const bf16x8*)(wr + 32), af1, acc, 0, 0, 0);
                    acc = __builtin_amdgcn_mfma_f32_16x16x32_bf16(*(const bf16x8*)(wr + 64), af2, acc, 0, 0, 0);
                    acc = __builtin_amdgcn_mfma_f32_16x16x32_bf16(*(const bf16x8*)(wr + 96), af3, acc, 0, 0, 0);
                    #pragma unroll
                    for (int r = 0; r < 4; ++r) acc[r] = acc[r] > 0.f ? acc[r] : 0.f;
                    *(uint2*)(myscr + scb(s, n * 2 + (q >> 1)) + (q & 1) * 4) = pk4(acc);
                }
                bf16x8 g0 = *(const bf16x8*)(myscr + scb(s, q));
                bf16x8 g1 = *(const bf16x8*)(myscr + scb(s, 4 + q));
                // 1x1 + residual (fp32)
                #pragma unroll
                for (int n = 0; n < 4; ++n) {
                    const int o0 = n * 16 + q * 4;
                    f32x4 r = *(const f32x4*)(cbj + o0);
                    const us* wr = cj + (n * 16 + s) * CC + q * 8;
                    r = __builtin_amdgcn_mfma_f32_16x16x32_bf16(*(const bf16x8*)(wr),      g0, r, 0, 0, 0);
                    r = __builtin_amdgcn_mfma_f32_16x16x32_bf16(*(const bf16x8*)(wr + 32), g1, r, 0, 0, 0);
                    r += *(const f32x4*)(sm + sws(tc + d, o0));
                    r2[fi][n] = r;
                }
                // in-chain skip: rows<96 owned by their tile; last tile owns the
                // overflow rows >=96 (their gt are reachable nowhere else).
                // skip16's [wb,Lend) gate excludes clamped/garbage rows.
                const bool own96 = (fi == 0 && wv < 6);
                if (own96 || lastt)
                    skip16(g0, g1, sj, sbj, opj, t0 + fg * 16,
                           Lj - SKIPN, Lj, s, q, 0, 16);
            }
        }
        __syncthreads();   // all sm/smb reads done
        #pragma unroll
        for (int fi = 0; fi < 2; ++fi) {
            const int fg = wv + fi * 8;
            const int t = fg * 16 + s;
            if (t < Rn) {
                #pragma unroll
                for (int n = 0; n < 4; ++n) {
                    const int o0 = n * 16 + q * 4;
                    *(f32x4*)(sm + sws(t, o0)) = r2[fi][n];
                    *(uint2*)(smb + swh(t, o0)) = pk4(r2[fi][n]);
                }
            }
        }
        __syncthreads();   // updates visible
        Rcur = Rn;
    }

    // final TOUT stream rows -> nxt
    float* dst = nxt + (size_t)b * LL0 * CC;
    for (int base = 0; base < TOUT; base += 32) {
        const int row = base + (tid >> 4);
        const int h4 = (tid & 15) * 4;
        const int gt = t0 + row;
        if (row < TOUT && gt < Lj)
            *(float4*)(dst + (size_t)gt * CC + h4) = *(const float4*)(sm + sws(row, h4));
    }
}

// ================= strip-fused pair kernel (256 threads) =================
template<int D>
__global__ __launch_bounds__(256) void pair_kernel(
    const float* __restrict__ cur, float* __restrict__ nxt,
    const us* __restrict__ wA, const us* __restrict__ wB,
    const us* __restrict__ cA, const us* __restrict__ cB,
    const float* __restrict__ dbA, const float* __restrict__ dbB,
    const float* __restrict__ cbA, const float* __restrict__ cbB,
    const us* __restrict__ swA, const us* __restrict__ swB,
    const float* __restrict__ sbA, const float* __restrict__ sbB,
    float* __restrict__ outA, float* __restrict__ outB,
    int Lin, int ntB)
{
    __shared__ __align__(16) us   xsb[4 * 32 * CC];
    __shared__ __align__(16) float xf[2 * 32 * CC];
    __shared__ __align__(16) us   msb[2 * 32 * CC];
    __shared__ __align__(16) float mf[32 * CC];
    __shared__ __align__(16) us   scr[4 * 16 * CC];

    const int tid = threadIdx.x, lane = tid & 63, wv = tid >> 6;
    const int b = blockIdx.x / ntB, T0 = (blockIdx.x % ntB) * 32;
    const float* src = cur + (size_t)b * LL0 * CC;
    const int s = lane & 15, q = lane >> 4;
    us* myscr = scr + wv * (16 * CC);
    const int LoutA = Lin - D, Lout2 = Lin - 3 * D;

    #pragma unroll
    for (int p = 0; p < 8; ++p) {
        const int row = p * 16 + (tid >> 4);
        const int st = row >> 5, r = row & 31;
        const int h4 = (tid & 15) * 4;
        int gt = T0 + st * D + r; if (gt > Lin - 1) gt = Lin - 1;
        f32x4 v = *(const f32x4*)(src + (size_t)gt * CC + h4);
        *(uint2*)(xsb + st * (32 * CC) + swh(r, h4)) = pk4(v);
        if (st & 1) *(f32x4*)(xf + (st >> 1) * (32 * CC) + sws(r, h4)) = v;
    }
    __syncthreads();

    // ---- A phase ----
    {
        const int m = wv >> 1, rA = (wv & 1) * 16 + s;
        const int tgrp = T0 + m * 2 * D + (wv & 1) * 16;
        const us* x0b = xsb + (2 * m) * (32 * CC);
        const us* x1b = xsb + (2 * m + 1) * (32 * CC);
        const float* x1f = xf + m * (32 * CC);
        bf16x8 af0 = *(const bf16x8*)(x0b + swh(rA, q * 8));
        bf16x8 af1 = *(const bf16x8*)(x0b + swh(rA, 32 + q * 8));
        bf16x8 af2 = *(const bf16x8*)(x1b + swh(rA, q * 8));
        bf16x8 af3 = *(const bf16x8*)(x1b + swh(rA, 32 + q * 8));
        #pragma unroll
        for (int n = 0; n < 4; ++n) {
            const int o0 = n * 16 + q * 4;
            f32x4 acc = *(const f32x4*)(dbA + o0);
            const us* wr = wA + (n * 16 + s) * 128 + q * 8;
            acc = __builtin_amdgcn_mfma_f32_16x16x32_bf16(*(const bf16x8*)(wr),      af0, acc, 0, 0, 0);
            acc = __builtin_amdgcn_mfma_f32_16x16x32_bf16(*(const bf16x8*)(wr + 32), af1, acc, 0, 0, 0);
            acc = __builtin_amdgcn_mfma_f32_16x16x32_bf16(*(const bf16x8*)(wr + 64), af2, acc, 0, 0, 0);
            acc = __builtin_amdgcn_mfma_f32_16x16x32_bf16(*(const bf16x8*)(wr + 96), af3, acc, 0, 0, 0);
            #pragma unroll
            for (int r = 0; r < 4; ++r) acc[r] = acc[r] > 0.f ? acc[r] : 0.f;
            *(uint2*)(myscr + scb(s, n * 2 + (q >> 1)) + (q & 1) * 4) = pk4(acc);
        }
        bf16x8 g0 = *(const bf16x8*)(myscr + scb(s, q));
        bf16x8 g1 = *(const bf16x8*)(myscr + scb(s, 4 + q));
        if (m == 0 || tgrp >= ntB * 32)
            skip16(g0, g1, swA, sbA, outA + (size_t)b * SCC * SKIPN,
                   tgrp, LoutA - SKIPN, LoutA, s, q, 0, 16);
        #pragma unroll
        for (int n = 0; n < 4; ++n) {
            const int o0 = n * 16 + q * 4;
            f32x4 r = *(const f32x4*)(cbA + o0);
            const us* wr = cA + (n * 16 + s) * CC + q * 8;
            r = __builtin_amdgcn_mfma_f32_16x16x32_bf16(*(const bf16x8*)(wr),      g0, r, 0, 0, 0);
            r = __builtin_amdgcn_mfma_f32_16x16x32_bf16(*(const bf16x8*)(wr + 32), g1, r, 0, 0, 0);
            r += *(const f32x4*)(x1f + sws(rA, o0));
            *(uint2*)(msb + m * (32 * CC) + swh(rA, o0)) = pk4(r);
            if (m == 1) *(f32x4*)(mf + sws(rA, o0)) = r;
        }
    }
    __syncthreads();

    // ---- B phase ----
    {
        const int rB = (wv & 1) * 16 + s;
        const int tB = T0 + rB;
        const int tgrp = T0 + (wv & 1) * 16;
        const bool lead = wv < 2;
        bf16x8 af0 = *(const bf16x8*)(msb + swh(rB, q * 8));
        bf16x8 af1 = *(const bf16x8*)(msb + swh(rB, 32 + q * 8));
        bf16x8 af2 = *(const bf16x8*)(msb + (32 * CC) + swh(rB, q * 8));
        bf16x8 af3 = *(const bf16x8*)(msb + (32 * CC) + swh(rB, 32 + q * 8));
        #pragma unroll
        for (int n = 0; n < 4; ++n) {
            const int o0 = n * 16 + q * 4;
            f32x4 acc = *(const f32x4*)(dbB + o0);
            const us* wr = wB + (n * 16 + s) * 128 + q * 8;
            acc = __builtin_amdgcn_mfma_f32_16x16x32_bf16(*(const bf16x8*)(wr),      af0, acc, 0, 0, 0);
            acc = __builtin_amdgcn_mfma_f32_16x16x32_bf16(*(const bf16x8*)(wr + 32), af1, acc, 0, 0, 0);
            acc = __builtin_amdgcn_mfma_f32_16x16x32_bf16(*(const bf16x8*)(wr + 64), af2, acc, 0, 0, 0);
            acc = __builtin_amdgcn_mfma_f32_16x16x32_bf16(*(const bf16x8*)(wr + 96), af3, acc, 0, 0, 0);
            #pragma unroll
            for (int r = 0; r < 4; ++r) acc[r] = acc[r] > 0.f ? acc[r] : 0.f;
            *(uint2*)(myscr + scb(s, n * 2 + (q >> 1)) + (q & 1) * 4) = pk4(acc);
        }
        bf16x8 g0 = *(const bf16x8*)(myscr + scb(s, q));
        bf16x8 g1 = *(const bf16x8*)(myscr + scb(s, 4 + q));
        skip16(g0, g1, swB, sbB, outB + (size_t)b * SCC * SKIPN,
               tgrp, Lout2 - SKIPN, Lout2, s, q, lead ? 0 : 8, lead ? 8 : 16);
        float* dst = nxt + (size_t)b * LL0 * CC;
        #pragma unroll
        for (int n = 0; n < 4; ++n) {
            const int o0 = n * 16 + q * 4;
            f32x4 r = *(const f32x4*)(cbB + o0);
            const us* wr = cB + (n * 16 + s) * CC + q * 8;
            r = __builtin_amdgcn_mfma_f32_16x16x32_bf16(*(const bf16x8*)(wr),      g0, r, 0, 0, 0);
            r = __builtin_amdgcn_mfma_f32_16x16x32_bf16(*(const bf16x8*)(wr + 32), g1, r, 0, 0, 0);
            r += *(const f32x4*)(mf + sws(rB, o0));
            if (lead && tB < Lout2)
                *(f32x4*)(dst + (size_t)tB * CC + o0) = r;
        }
    }
}

extern "C" void kernel_launch(void* const* d_in, const int* in_sizes, int n_in,
                              void* d_out, int out_size, void* d_ws, size_t ws_size,
                              hipStream_t stream)
{
    const float* x      = (const float*)d_in[0];
    const float* dc_w   = (const float*)d_in[1];
    const float* dc_b   = (const float*)d_in[2];
    const float* conv_w = (const float*)d_in[3];
    const float* conv_b = (const float*)d_in[4];
    const float* skip_w = (const float*)d_in[5];
    const float* skip_b = (const float*)d_in[6];
    float* out = (float*)d_out;

    char* ws = (char*)d_ws;
    float* bufA = (float*)ws;  ws += (size_t)BB * LL0 * CC * 4;
    float* bufB = (float*)ws;  ws += (size_t)BB * LL0 * CC * 4;
    us* wcat = (us*)ws;        ws += (size_t)NBLK * CC * 128 * 2;
    us* cwb  = (us*)ws;        ws += (size_t)NBLK * CC * CC * 2;
    us* swb  = (us*)ws;        ws += (size_t)NBLK * SCC * CC * 2;

    prep_kernel<<<1536, 256, 0, stream>>>(x, bufA, dc_w, conv_w, skip_w, wcat, cwb, swb);

    float* bufs[2] = {bufA, bufB};
    const size_t OSZ = (size_t)BB * SCC * SKIPN;
    int Lc = LL0, blk = 0, qq = 0;
    for (int st = 0; st < 4; ++st) {
        {   // fused d=1..32 (blocks blk..blk+5)
            const int Lout = Lc - 63;
            const int nt = (Lout + 95) / 96;
            fused6_kernel<<<dim3(BB * nt), 512, 0, stream>>>(
                bufs[qq & 1], bufs[(qq + 1) & 1], wcat, cwb, dc_b, conv_b,
                swb, skip_b, out, blk, Lc, nt);
            blk += 6; Lc = Lout; ++qq;
        }
        for (int pi = 0; pi < 2; ++pi) {  // pair<64> then pair<256>
            const int D = pi == 0 ? 64 : 256;
            const int Lout2 = Lc - 3 * D;
            const int nt = (Lout2 + 31) / 32;
            if (D == 64)
                pair_kernel<64><<<dim3(BB * nt), 256, 0, stream>>>(
                    bufs[qq & 1], bufs[(qq + 1) & 1],
                    wcat + (size_t)blk * CC * 128, wcat + (size_t)(blk + 1) * CC * 128,
                    cwb + (size_t)blk * CC * CC, cwb + (size_t)(blk + 1) * CC * CC,
                    dc_b + blk * CC, dc_b + (blk + 1) * CC,
                    conv_b + blk * CC, conv_b + (blk + 1) * CC,
                    swb + (size_t)blk * SCC * CC, swb + (size_t)(blk + 1) * SCC * CC,
                    skip_b + blk * SCC, skip_b + (blk + 1) * SCC,
                    out + (size_t)blk * OSZ, out + (size_t)(blk + 1) * OSZ,
                    Lc, nt);
            else
                pair_kernel<256><<<dim3(BB * nt), 256, 0, stream>>>(
                    bufs[qq & 1], bufs[(qq + 1) & 1],
                    wcat + (size_t)blk * CC * 128, wcat + (size_t)(blk + 1) * CC * 128,
                    cwb + (size_t)blk * CC * CC, cwb + (size_t)(blk + 1) * CC * CC,
                    dc_b + blk * CC, dc_b + (blk + 1) * CC,
                    conv_b + blk * CC, conv_b + (blk + 1) * CC,
                    swb + (size_t)blk * SCC * CC, swb + (size_t)(blk + 1) * SCC * CC,
                    skip_b + blk * SCC, skip_b + (blk + 1) * SCC,
                    out + (size_t)blk * OSZ, out + (size_t)(blk + 1) * OSZ,
                    Lc, nt);
            blk += 2; Lc = Lout2; ++qq;
        }
    }
}

// Round 11
// 853.990 us; speedup vs baseline: 1.1888x; 1.1888x over previous
//
#include <hip/hip_runtime.h>

// WaveNet residual stack, MFMA bf16. 21 chain dispatches + prep + skip tail:
//   per stack: fused6 (d=1..32, halo in LDS, 2 barriers/block)
//            + 4 singles (d=64..512, ONE barrier, direct global stores).
// Skip GEMMs run as piggyback WGs (lag>=1 launch, cap 4 blocks) reading g_all.
// Stream fp32 [b][t][c] with bf16 LDS shadows; wave-private g scratch.

#define CC    64
#define SCC   256
#define BB    4
#define LL0   8192
#define NBLK  40
#define SKIPN 4096

typedef __attribute__((ext_vector_type(8))) short bf16x8;
typedef __attribute__((ext_vector_type(4))) float f32x4;
typedef unsigned short us;

__device__ __forceinline__ us f2bf(float f) {
    union { float f; unsigned u; } v; v.f = f;
    return (us)((v.u + 0x7FFF + ((v.u >> 16) & 1)) >> 16);
}
__device__ __forceinline__ unsigned pk2(float a, float b) {
    return (unsigned)f2bf(a) | ((unsigned)f2bf(b) << 16);
}
__device__ __forceinline__ uint2 pk4(f32x4 v) {
    return (uint2){pk2(v[0], v[1]), pk2(v[2], v[3])};
}
// fp32 [row][64] LDS word index, 32B-chunk XOR swizzle
__device__ __forceinline__ int sws(int r, int c) {
    return (r << 6) + ((((c >> 3) ^ r) & 7) << 3) + (c & 7);
}
// bf16 [row][64] LDS elem index, 16B-chunk XOR swizzle
__device__ __forceinline__ int swh(int r, int c) {
    return (r << 6) + ((((c >> 3) ^ r) & 7) << 3) + (c & 7);
}
// wave-private bf16 scratch [16 rows][64 c], 16B-chunk XOR swizzle
__device__ __forceinline__ int scb(int s, int chunk) {
    return (s << 6) + (((chunk ^ (s & 7)) & 7) << 3);
}

// ---- merged prep: x transpose [b][c][t]->[b][t][c] + weight bf16 casts ----
__global__ __launch_bounds__(256) void prep_kernel(
    const float* __restrict__ x, float* __restrict__ xt_out,
    const float* __restrict__ dc_w, const float* __restrict__ conv_w,
    const float* __restrict__ skip_w,
    us* __restrict__ wcat, us* __restrict__ cwb, us* __restrict__ swb)
{
    if (blockIdx.x < 512) {
        __shared__ float tile[64][65];
        const int b = blockIdx.x >> 7, t0 = (blockIdx.x & 127) * 64;
        const int tid = threadIdx.x;
        #pragma unroll
        for (int p = 0; p < 4; ++p) {
            const int c = p * 16 + (tid >> 4), j = tid & 15;
            const float4 v = *(const float4*)(x + ((size_t)b * CC + c) * LL0 + t0 + j * 4);
            tile[c][j*4+0]=v.x; tile[c][j*4+1]=v.y; tile[c][j*4+2]=v.z; tile[c][j*4+3]=v.w;
        }
        __syncthreads();
        #pragma unroll
        for (int p = 0; p < 4; ++p) {
            const int r = p * 16 + (tid >> 4), h = tid & 15;
            float4 v = {tile[h*4+0][r], tile[h*4+1][r], tile[h*4+2][r], tile[h*4+3][r]};
            *(float4*)(xt_out + ((size_t)b * LL0 + t0 + r) * CC + h * 4) = v;
        }
        return;
    }
    const int n_sw = NBLK * SCC * CC, n_cw = NBLK * CC * CC, n_wc = NBLK * CC * 128;
    for (int idx = (blockIdx.x - 512) * blockDim.x + threadIdx.x; idx < n_sw;
         idx += 1024 * blockDim.x) {
        swb[idx] = f2bf(skip_w[idx]);
        if (idx < n_cw) cwb[idx] = f2bf(conv_w[idx]);
        if (idx < n_wc) {
            const int i = idx >> 13, o = (idx >> 7) & 63, kk = idx & 127;
            wcat[idx] = f2bf(dc_w[(((i * CC + o) * CC) + (kk & 63)) * 2 + (kk >> 6)]);
        }
    }
}

// ---- skip GEMM piggyback body; 8 waves, 128-row tile => 128 WGs/block ----
__device__ __forceinline__ void skip_body8(
    int e, int blk0,
    const us* __restrict__ g_all, const us* __restrict__ swb,
    const float* __restrict__ skip_b, float* __restrict__ out)
{
    constexpr int ROWS = 128;
    constexpr int TPB = (SKIPN / ROWS) * BB;   // 128
    const int tid = threadIdx.x, lane = tid & 63, wv = tid >> 6;
    const int j = blk0 + e / TPB;
    const int id = e % TPB;
    const int tt = id % (SKIPN / ROWS);
    const int b  = id / (SKIPN / ROWS);
    const us* g  = g_all + ((size_t)j * BB + b) * SKIPN * CC;
    const us* sw = swb + (size_t)j * SCC * CC;
    const float* sb = skip_b + j * SCC;
    float* op = out + ((size_t)j * BB + b) * SCC * SKIPN;

    const int trow = tt * ROWS + wv * 16 + (lane & 15);
    bf16x8 a[2];
    a[0] = *(const bf16x8*)(g + (size_t)trow * CC + (lane >> 4) * 8);
    a[1] = *(const bf16x8*)(g + (size_t)trow * CC + 32 + (lane >> 4) * 8);
    const int tstore = tt * ROWS + wv * 16 + ((lane >> 4) << 2);
    #pragma unroll 4
    for (int n = 0; n < 16; ++n) {
        const int sc = n * 16 + (lane & 15);
        const float bias = sb[sc];
        f32x4 acc = (f32x4){bias, bias, bias, bias};
        const us* wrow = sw + sc * CC + (lane >> 4) * 8;
        acc = __builtin_amdgcn_mfma_f32_16x16x32_bf16(a[0], *(const bf16x8*)(wrow), acc, 0, 0, 0);
        acc = __builtin_amdgcn_mfma_f32_16x16x32_bf16(a[1], *(const bf16x8*)(wrow + 32), acc, 0, 0, 0);
        *(float4*)(op + (size_t)sc * SKIPN + tstore) = (float4){acc[0], acc[1], acc[2], acc[3]};
    }
}

// ================= fused d=1..32 kernel (512 threads) =================
// sm fp32 40KB + smb bf16 20KB + scr 16KB = 76KB. 2 barriers/block.
__global__ __launch_bounds__(512) void fused6_kernel(
    const float* __restrict__ cur, float* __restrict__ nxt,
    const us* __restrict__ wcat_all, const us* __restrict__ cwb_all,
    const float* __restrict__ db_all, const float* __restrict__ cb_all,
    us* __restrict__ g_all, int blk0, int Lin, int ntiles,
    const us* __restrict__ swb, const float* __restrict__ skip_b,
    float* __restrict__ out, int pb0)
{
    const int wg = blockIdx.x, chain = BB * ntiles;
    if (wg >= chain) { skip_body8(wg - chain, pb0, g_all, swb, skip_b, out); return; }

    constexpr int TOUT = 96, R0 = 159, RCAP = 160;
    __shared__ __align__(16) float sm[RCAP * CC];
    __shared__ __align__(16) us  smb[RCAP * CC];
    __shared__ __align__(16) us  scr[8 * 16 * CC];

    const int tid = threadIdx.x, lane = tid & 63, wv = tid >> 6;
    const int b = wg / ntiles, t0 = (wg % ntiles) * TOUT;
    const float* src = cur + (size_t)b * LL0 * CC;
    const int s = lane & 15, q = lane >> 4;
    us* myscr = scr + wv * (16 * CC);

    for (int base = 0; base < R0; base += 32) {
        const int row = base + (tid >> 4);
        const int h4 = (tid & 15) * 4;
        if (row < R0) {
            int gt = t0 + row; if (gt > Lin - 1) gt = Lin - 1;
            f32x4 v = *(const f32x4*)(src + (size_t)gt * CC + h4);
            *(f32x4*)(sm + sws(row, h4)) = v;
            *(uint2*)(smb + swh(row, h4)) = pk4(v);
        }
    }
    __syncthreads();

    int Rcur = R0, Lj = Lin;
    for (int j = 0; j < 6; ++j) {
        const int d = 1 << j;
        const int Rn = Rcur - d;
        Lj -= d;
        const us* wj = wcat_all + (size_t)(blk0 + j) * CC * 128;
        const us* cj = cwb_all + (size_t)(blk0 + j) * CC * CC;
        const float* dbj = db_all + (blk0 + j) * CC;
        const float* cbj = cb_all + (blk0 + j) * CC;
        const int wbase = Lj - SKIPN;
        us* gdst = g_all + ((size_t)(blk0 + j) * BB + b) * SKIPN * CC;

        f32x4 r2[2][4];
        #pragma unroll
        for (int fi = 0; fi < 2; ++fi) {
            const int fg = wv + fi * 8;
            if (fg * 16 < Rn) {
                const int t = fg * 16 + s;
                const int tc = t > Rn - 1 ? Rn - 1 : t;
                bf16x8 af0 = *(const bf16x8*)(smb + swh(tc,     q * 8));
                bf16x8 af1 = *(const bf16x8*)(smb + swh(tc,     32 + q * 8));
                bf16x8 af2 = *(const bf16x8*)(smb + swh(tc + d, q * 8));
                bf16x8 af3 = *(const bf16x8*)(smb + swh(tc + d, 32 + q * 8));
                #pragma unroll
                for (int n = 0; n < 4; ++n) {
                    const int o0 = n * 16 + q * 4;
                    f32x4 acc = *(const f32x4*)(dbj + o0);
                    const us* wr = wj + (n * 16 + s) * 128 + q * 8;
                    acc = __builtin_amdgcn_mfma_f32_16x16x32_bf16(*(const bf16x8*)(wr),      af0, acc, 0, 0, 0);
                    acc = __builtin_amdgcn_mfma_f32_16x16x32_bf16(*(const bf16x8*)(wr + 32), af1, acc, 0, 0, 0);
                    acc = __builtin_amdgcn_mfma_f32_16x16x32_bf16(*(const bf16x8*)(wr + 64), af2, acc, 0, 0, 0);
                    acc = __builtin_amdgcn_mfma_f32_16x16x32_bf16(*(const bf16x8*)(wr + 96), af3, acc, 0, 0, 0);
                    #pragma unroll
                    for (int r = 0; r < 4; ++r) acc[r] = acc[r] > 0.f ? acc[r] : 0.f;
                    *(uint2*)(myscr + scb(s, n * 2 + (q >> 1)) + (q & 1) * 4) = pk4(acc);
                }
                bf16x8 g0 = *(const bf16x8*)(myscr + scb(s, q));
                bf16x8 g1 = *(const bf16x8*)(myscr + scb(s, 4 + q));
                // g window store (duplicate rows across tiles write identical bytes)
                {
                    const int gt = t0 + t;
                    if (t < Rn && gt >= wbase && gt < Lj) {
                        us* gr = gdst + (size_t)(gt - wbase) * CC;
                        #pragma unroll
                        for (int h = 0; h < 2; ++h) {
                            const int ck = q * 2 + h;
                            *(bf16x8*)(gr + ck * 8) = *(const bf16x8*)(myscr + scb(s, ck));
                        }
                    }
                }
                #pragma unroll
                for (int n = 0; n < 4; ++n) {
                    const int o0 = n * 16 + q * 4;
                    f32x4 r = *(const f32x4*)(cbj + o0);
                    const us* wr = cj + (n * 16 + s) * CC + q * 8;
                    r = __builtin_amdgcn_mfma_f32_16x16x32_bf16(*(const bf16x8*)(wr),      g0, r, 0, 0, 0);
                    r = __builtin_amdgcn_mfma_f32_16x16x32_bf16(*(const bf16x8*)(wr + 32), g1, r, 0, 0, 0);
                    r += *(const f32x4*)(sm + sws(tc + d, o0));
                    r2[fi][n] = r;
                }
            }
        }
        __syncthreads();
        #pragma unroll
        for (int fi = 0; fi < 2; ++fi) {
            const int fg = wv + fi * 8;
            const int t = fg * 16 + s;
            if (t < Rn) {
                #pragma unroll
                for (int n = 0; n < 4; ++n) {
                    const int o0 = n * 16 + q * 4;
                    *(f32x4*)(sm + sws(t, o0)) = r2[fi][n];
                    *(uint2*)(smb + swh(t, o0)) = pk4(r2[fi][n]);
                }
            }
        }
        __syncthreads();
        Rcur = Rn;
    }

    float* dst = nxt + (size_t)b * LL0 * CC;
    for (int base = 0; base < TOUT; base += 32) {
        const int row = base + (tid >> 4);
        const int h4 = (tid & 15) * 4;
        const int gt = t0 + row;
        if (row < TOUT && gt < Lj)
            *(float4*)(dst + (size_t)gt * CC + h4) = *(const float4*)(sm + sws(row, h4));
    }
}

// ================= single-block kernel (512 threads, TTC=64, ONE barrier) ======
// xb0/xb1 bf16 8KB each + x1f fp32 16KB + scr 16KB = 48KB -> 3 WGs/CU.
__global__ __launch_bounds__(512) void single_kernel(
    const float* __restrict__ cur, float* __restrict__ nxt,
    const us* __restrict__ wcat, const us* __restrict__ cwb,
    const float* __restrict__ db, const float* __restrict__ cb,
    us* __restrict__ g_out,
    int d, int Lin, int Lout, int ntiles,
    const us* __restrict__ g_all, const us* __restrict__ swb,
    const float* __restrict__ skip_b, float* __restrict__ out, int pb0)
{
    const int wg = blockIdx.x, chain = BB * ntiles;
    if (wg >= chain) { skip_body8(wg - chain, pb0, g_all, swb, skip_b, out); return; }

    __shared__ __align__(16) us   xb0[64 * CC];
    __shared__ __align__(16) us   xb1[64 * CC];
    __shared__ __align__(16) float x1f[64 * CC];
    __shared__ __align__(16) us   scr[8 * 16 * CC];

    const int tid = threadIdx.x, lane = tid & 63, wv = tid >> 6;
    const int b = wg / ntiles, t0 = (wg % ntiles) * 64;
    const float* src = cur + (size_t)b * LL0 * CC;
    const int s = lane & 15, q = lane >> 4;
    us* myscr = scr + wv * (16 * CC);
    const int Lv = (Lout - t0) < 64 ? (Lout - t0) : 64;   // valid rows this tile

    // ---- stage both taps (bf16 shadows; tap-1 also fp32) ----
    #pragma unroll
    for (int p = 0; p < 2; ++p) {
        const int row = p * 32 + (tid >> 4);
        const int h4 = (tid & 15) * 4;
        int ta = t0 + row;     if (ta > Lin - 1) ta = Lin - 1;
        int tb = t0 + row + d; if (tb > Lin - 1) tb = Lin - 1;
        f32x4 v0 = *(const f32x4*)(src + (size_t)ta * CC + h4);
        f32x4 v1 = *(const f32x4*)(src + (size_t)tb * CC + h4);
        *(uint2*)(xb0 + swh(row, h4)) = pk4(v0);
        *(uint2*)(xb1 + swh(row, h4)) = pk4(v1);
        *(f32x4*)(x1f + sws(row, h4)) = v1;
    }
    __syncthreads();   // the only barrier

    // ---- wave-local: conv -> g scratch -> {g store, 1x1 + residual -> global} ----
    const int tl = wv * 16 + s;                     // local row this lane computes
    const int tc = tl > Lv - 1 ? Lv - 1 : tl;       // clamped for frag reads
    bf16x8 af0 = *(const bf16x8*)(xb0 + swh(tc, q * 8));
    bf16x8 af1 = *(const bf16x8*)(xb0 + swh(tc, 32 + q * 8));
    bf16x8 af2 = *(const bf16x8*)(xb1 + swh(tc, q * 8));
    bf16x8 af3 = *(const bf16x8*)(xb1 + swh(tc, 32 + q * 8));
    #pragma unroll
    for (int n = 0; n < 4; ++n) {
        const int o0 = n * 16 + q * 4;
        f32x4 acc = *(const f32x4*)(db + o0);
        const us* wr = wcat + (n * 16 + s) * 128 + q * 8;
        acc = __builtin_amdgcn_mfma_f32_16x16x32_bf16(*(const bf16x8*)(wr),      af0, acc, 0, 0, 0);
        acc = __builtin_amdgcn_mfma_f32_16x16x32_bf16(*(const bf16x8*)(wr + 32), af1, acc, 0, 0, 0);
        acc = __builtin_amdgcn_mfma_f32_16x16x32_bf16(*(const bf16x8*)(wr + 64), af2, acc, 0, 0, 0);
        acc = __builtin_amdgcn_mfma_f32_16x16x32_bf16(*(const bf16x8*)(wr + 96), af3, acc, 0, 0, 0);
        #pragma unroll
        for (int r = 0; r < 4; ++r) acc[r] = acc[r] > 0.f ? acc[r] : 0.f;
        *(uint2*)(myscr + scb(s, n * 2 + (q >> 1)) + (q & 1) * 4) = pk4(acc);
    }
    bf16x8 g0 = *(const bf16x8*)(myscr + scb(s, q));
    bf16x8 g1 = *(const bf16x8*)(myscr + scb(s, 4 + q));
    // g window store straight from scratch
    {
        const int gt = t0 + tl;
        const int wb = Lout - SKIPN;
        if (tl < Lv && gt >= wb) {
            us* gr = g_out + ((size_t)b * SKIPN + (gt - wb)) * CC;
            #pragma unroll
            for (int h = 0; h < 2; ++h) {
                const int ck = q * 2 + h;
                *(bf16x8*)(gr + ck * 8) = *(const bf16x8*)(myscr + scb(s, ck));
            }
        }
    }
    // 1x1 + residual -> direct global store
    float* dst = nxt + (size_t)b * LL0 * CC + (size_t)(t0 + tl) * CC;
    #pragma unroll
    for (int n = 0; n < 4; ++n) {
        const int o0 = n * 16 + q * 4;
        f32x4 r = *(const f32x4*)(cb + o0);
        const us* wr = cwb + (n * 16 + s) * CC + q * 8;
        r = __builtin_amdgcn_mfma_f32_16x16x32_bf16(*(const bf16x8*)(wr),      g0, r, 0, 0, 0);
        r = __builtin_amdgcn_mfma_f32_16x16x32_bf16(*(const bf16x8*)(wr + 32), g1, r, 0, 0, 0);
        r += *(const f32x4*)(x1f + sws(tl < 63 ? tl : 63, o0));
        if (tl < Lv) *(f32x4*)(dst + o0) = r;
    }
}

__global__ __launch_bounds__(512) void skip_kernel(
    const us* __restrict__ g_all, const us* __restrict__ swb,
    const float* __restrict__ skip_b, float* __restrict__ out, int blk0)
{
    skip_body8(blockIdx.x, blk0, g_all, swb, skip_b, out);
}

extern "C" void kernel_launch(void* const* d_in, const int* in_sizes, int n_in,
                              void* d_out, int out_size, void* d_ws, size_t ws_size,
                              hipStream_t stream)
{
    const float* x      = (const float*)d_in[0];
    const float* dc_w   = (const float*)d_in[1];
    const float* dc_b   = (const float*)d_in[2];
    const float* conv_w = (const float*)d_in[3];
    const float* conv_b = (const float*)d_in[4];
    const float* skip_w = (const float*)d_in[5];
    const float* skip_b = (const float*)d_in[6];
    float* out = (float*)d_out;

    char* ws = (char*)d_ws;
    float* bufA = (float*)ws;  ws += (size_t)BB * LL0 * CC * 4;
    float* bufB = (float*)ws;  ws += (size_t)BB * LL0 * CC * 4;
    us* g_all = (us*)ws;       ws += (size_t)NBLK * BB * SKIPN * CC * 2;
    us* wcat = (us*)ws;        ws += (size_t)NBLK * CC * 128 * 2;
    us* cwb  = (us*)ws;        ws += (size_t)NBLK * CC * CC * 2;
    us* swb  = (us*)ws;        ws += (size_t)NBLK * SCC * CC * 2;

    prep_kernel<<<1536, 256, 0, stream>>>(x, bufA, dc_w, conv_w, skip_w, wcat, cwb, swb);

    float* bufs[2] = {bufA, bufB};
    const size_t GSZ = (size_t)BB * SKIPN * CC;
    int Lc = LL0, blk = 0, qq = 0, produced = 0, skipped = 0;
    for (int st = 0; st < 4; ++st) {
        {   // fused d=1..32
            const int Lout = Lc - 63;
            const int nt = (Lout + 95) / 96;
            int cap = produced - skipped; if (cap > 4) cap = 4;
            fused6_kernel<<<dim3(BB * nt + cap * 128), 512, 0, stream>>>(
                bufs[qq & 1], bufs[(qq + 1) & 1], wcat, cwb, dc_b, conv_b,
                g_all, blk, Lc, nt, swb, skip_b, out, skipped);
            skipped += cap; produced += 6; blk += 6; Lc = Lout; ++qq;
        }
        for (int dl = 6; dl < 10; ++dl) {   // d = 64..512 singles
            const int d = 1 << dl;
            const int Lout = Lc - d;
            const int nt = (Lout + 63) / 64;
            int cap = produced - skipped; if (cap > 4) cap = 4;
            single_kernel<<<dim3(BB * nt + cap * 128), 512, 0, stream>>>(
                bufs[qq & 1], bufs[(qq + 1) & 1],
                wcat + (size_t)blk * CC * 128, cwb + (size_t)blk * CC * CC,
                dc_b + blk * CC, conv_b + blk * CC,
                g_all + (size_t)blk * GSZ,
                d, Lc, Lout, nt, g_all, swb, skip_b, out, skipped);
            skipped += cap; produced += 1; blk += 1; Lc = Lout; ++qq;
        }
    }
    const int rem = NBLK - skipped;
    if (rem > 0)
        skip_kernel<<<dim3(rem * 128), 512, 0, stream>>>(g_all, swb, skip_b, out, skipped);
}

// Round 12
// 834.638 us; speedup vs baseline: 1.2163x; 1.0232x over previous
//
#include <hip/hip_runtime.h>

// WaveNet residual stack, MFMA bf16. 14 dispatches:
//   prep + per stack { fused6 (d=1..32) + pair<64> + pair<256> } (12 lean chain
//   launches, NO piggyback) + ONE big skip kernel (all 40 blocks, 10240 WGs).
// Chain writes g windows (bf16) to g_all; skip kernel is HBM-write-bound and
// massively parallel. Stream fp32 [b][t][c] with bf16 LDS shadows.

#define CC    64
#define SCC   256
#define BB    4
#define LL0   8192
#define NBLK  40
#define SKIPN 4096

typedef __attribute__((ext_vector_type(8))) short bf16x8;
typedef __attribute__((ext_vector_type(4))) float f32x4;
typedef unsigned short us;

__device__ __forceinline__ us f2bf(float f) {
    union { float f; unsigned u; } v; v.f = f;
    return (us)((v.u + 0x7FFF + ((v.u >> 16) & 1)) >> 16);
}
__device__ __forceinline__ unsigned pk2(float a, float b) {
    return (unsigned)f2bf(a) | ((unsigned)f2bf(b) << 16);
}
__device__ __forceinline__ uint2 pk4(f32x4 v) {
    return (uint2){pk2(v[0], v[1]), pk2(v[2], v[3])};
}
// fp32 [row][64] LDS word index, 32B-chunk XOR swizzle
__device__ __forceinline__ int sws(int r, int c) {
    return (r << 6) + ((((c >> 3) ^ r) & 7) << 3) + (c & 7);
}
// bf16 [row][64] LDS elem index, 16B-chunk XOR swizzle
__device__ __forceinline__ int swh(int r, int c) {
    return (r << 6) + ((((c >> 3) ^ r) & 7) << 3) + (c & 7);
}
// wave-private bf16 scratch [16 rows][64 c], 16B-chunk XOR swizzle
__device__ __forceinline__ int scb(int s, int chunk) {
    return (s << 6) + (((chunk ^ (s & 7)) & 7) << 3);
}

// ---- merged prep: x transpose [b][c][t]->[b][t][c] + weight bf16 casts ----
__global__ __launch_bounds__(256) void prep_kernel(
    const float* __restrict__ x, float* __restrict__ xt_out,
    const float* __restrict__ dc_w, const float* __restrict__ conv_w,
    const float* __restrict__ skip_w,
    us* __restrict__ wcat, us* __restrict__ cwb, us* __restrict__ swb)
{
    if (blockIdx.x < 512) {
        __shared__ float tile[64][65];
        const int b = blockIdx.x >> 7, t0 = (blockIdx.x & 127) * 64;
        const int tid = threadIdx.x;
        #pragma unroll
        for (int p = 0; p < 4; ++p) {
            const int c = p * 16 + (tid >> 4), j = tid & 15;
            const float4 v = *(const float4*)(x + ((size_t)b * CC + c) * LL0 + t0 + j * 4);
            tile[c][j*4+0]=v.x; tile[c][j*4+1]=v.y; tile[c][j*4+2]=v.z; tile[c][j*4+3]=v.w;
        }
        __syncthreads();
        #pragma unroll
        for (int p = 0; p < 4; ++p) {
            const int r = p * 16 + (tid >> 4), h = tid & 15;
            float4 v = {tile[h*4+0][r], tile[h*4+1][r], tile[h*4+2][r], tile[h*4+3][r]};
            *(float4*)(xt_out + ((size_t)b * LL0 + t0 + r) * CC + h * 4) = v;
        }
        return;
    }
    const int n_sw = NBLK * SCC * CC, n_cw = NBLK * CC * CC, n_wc = NBLK * CC * 128;
    for (int idx = (blockIdx.x - 512) * blockDim.x + threadIdx.x; idx < n_sw;
         idx += 1024 * blockDim.x) {
        swb[idx] = f2bf(skip_w[idx]);
        if (idx < n_cw) cwb[idx] = f2bf(conv_w[idx]);
        if (idx < n_wc) {
            const int i = idx >> 13, o = (idx >> 7) & 63, kk = idx & 127;
            wcat[idx] = f2bf(dc_w[(((i * CC + o) * CC) + (kk & 63)) * 2 + (kk >> 6)]);
        }
    }
}

// ================= fused d=1..32 kernel (512 threads, lean grid) ==============
__global__ __launch_bounds__(512) void fused6_kernel(
    const float* __restrict__ cur, float* __restrict__ nxt,
    const us* __restrict__ wcat_all, const us* __restrict__ cwb_all,
    const float* __restrict__ db_all, const float* __restrict__ cb_all,
    us* __restrict__ g_all, int blk0, int Lin, int ntiles)
{
    constexpr int TOUT = 96, R0 = 159, RCAP = 160;
    __shared__ __align__(16) float sm[RCAP * CC];
    __shared__ __align__(16) us  smb[RCAP * CC];
    __shared__ __align__(16) us  scr[8 * 16 * CC];

    const int tid = threadIdx.x, lane = tid & 63, wv = tid >> 6;
    const int b = blockIdx.x / ntiles, t0 = (blockIdx.x % ntiles) * TOUT;
    const float* src = cur + (size_t)b * LL0 * CC;
    const int s = lane & 15, q = lane >> 4;
    us* myscr = scr + wv * (16 * CC);

    for (int base = 0; base < R0; base += 32) {
        const int row = base + (tid >> 4);
        const int h4 = (tid & 15) * 4;
        if (row < R0) {
            int gt = t0 + row; if (gt > Lin - 1) gt = Lin - 1;
            f32x4 v = *(const f32x4*)(src + (size_t)gt * CC + h4);
            *(f32x4*)(sm + sws(row, h4)) = v;
            *(uint2*)(smb + swh(row, h4)) = pk4(v);
        }
    }
    __syncthreads();

    int Rcur = R0, Lj = Lin;
    for (int j = 0; j < 6; ++j) {
        const int d = 1 << j;
        const int Rn = Rcur - d;
        Lj -= d;
        const us* wj = wcat_all + (size_t)(blk0 + j) * CC * 128;
        const us* cj = cwb_all + (size_t)(blk0 + j) * CC * CC;
        const float* dbj = db_all + (blk0 + j) * CC;
        const float* cbj = cb_all + (blk0 + j) * CC;
        const int wbase = Lj - SKIPN;
        us* gdst = g_all + ((size_t)(blk0 + j) * BB + b) * SKIPN * CC;

        f32x4 r2[2][4];
        #pragma unroll
        for (int fi = 0; fi < 2; ++fi) {
            const int fg = wv + fi * 8;
            if (fg * 16 < Rn) {
                const int t = fg * 16 + s;
                const int tc = t > Rn - 1 ? Rn - 1 : t;
                bf16x8 af0 = *(const bf16x8*)(smb + swh(tc,     q * 8));
                bf16x8 af1 = *(const bf16x8*)(smb + swh(tc,     32 + q * 8));
                bf16x8 af2 = *(const bf16x8*)(smb + swh(tc + d, q * 8));
                bf16x8 af3 = *(const bf16x8*)(smb + swh(tc + d, 32 + q * 8));
                #pragma unroll
                for (int n = 0; n < 4; ++n) {
                    const int o0 = n * 16 + q * 4;
                    f32x4 acc = *(const f32x4*)(dbj + o0);
                    const us* wr = wj + (n * 16 + s) * 128 + q * 8;
                    acc = __builtin_amdgcn_mfma_f32_16x16x32_bf16(*(const bf16x8*)(wr),      af0, acc, 0, 0, 0);
                    acc = __builtin_amdgcn_mfma_f32_16x16x32_bf16(*(const bf16x8*)(wr + 32), af1, acc, 0, 0, 0);
                    acc = __builtin_amdgcn_mfma_f32_16x16x32_bf16(*(const bf16x8*)(wr + 64), af2, acc, 0, 0, 0);
                    acc = __builtin_amdgcn_mfma_f32_16x16x32_bf16(*(const bf16x8*)(wr + 96), af3, acc, 0, 0, 0);
                    #pragma unroll
                    for (int r = 0; r < 4; ++r) acc[r] = acc[r] > 0.f ? acc[r] : 0.f;
                    *(uint2*)(myscr + scb(s, n * 2 + (q >> 1)) + (q & 1) * 4) = pk4(acc);
                }
                bf16x8 g0 = *(const bf16x8*)(myscr + scb(s, q));
                bf16x8 g1 = *(const bf16x8*)(myscr + scb(s, 4 + q));
                // g window store (duplicate rows across tiles write identical bytes)
                {
                    const int gt = t0 + t;
                    if (t < Rn && gt >= wbase && gt < Lj) {
                        us* gr = gdst + (size_t)(gt - wbase) * CC;
                        #pragma unroll
                        for (int h = 0; h < 2; ++h) {
                            const int ck = q * 2 + h;
                            *(bf16x8*)(gr + ck * 8) = *(const bf16x8*)(myscr + scb(s, ck));
                        }
                    }
                }
                #pragma unroll
                for (int n = 0; n < 4; ++n) {
                    const int o0 = n * 16 + q * 4;
                    f32x4 r = *(const f32x4*)(cbj + o0);
                    const us* wr = cj + (n * 16 + s) * CC + q * 8;
                    r = __builtin_amdgcn_mfma_f32_16x16x32_bf16(*(const bf16x8*)(wr),      g0, r, 0, 0, 0);
                    r = __builtin_amdgcn_mfma_f32_16x16x32_bf16(*(const bf16x8*)(wr + 32), g1, r, 0, 0, 0);
                    r += *(const f32x4*)(sm + sws(tc + d, o0));
                    r2[fi][n] = r;
                }
            }
        }
        __syncthreads();
        #pragma unroll
        for (int fi = 0; fi < 2; ++fi) {
            const int fg = wv + fi * 8;
            const int t = fg * 16 + s;
            if (t < Rn) {
                #pragma unroll
                for (int n = 0; n < 4; ++n) {
                    const int o0 = n * 16 + q * 4;
                    *(f32x4*)(sm + sws(t, o0)) = r2[fi][n];
                    *(uint2*)(smb + swh(t, o0)) = pk4(r2[fi][n]);
                }
            }
        }
        __syncthreads();
        Rcur = Rn;
    }

    float* dst = nxt + (size_t)b * LL0 * CC;
    for (int base = 0; base < TOUT; base += 32) {
        const int row = base + (tid >> 4);
        const int h4 = (tid & 15) * 4;
        const int gt = t0 + row;
        if (row < TOUT && gt < Lj)
            *(float4*)(dst + (size_t)gt * CC + h4) = *(const float4*)(sm + sws(row, h4));
    }
}

// ================= strip-fused pair kernel (256 threads, lean grid) ===========
// blocks (d=D, d=2D). Strips of 32 rows at offsets {0,D,2D,3D}. 2 barriers.
template<int D>
__global__ __launch_bounds__(256) void pair_kernel(
    const float* __restrict__ cur, float* __restrict__ nxt,
    const us* __restrict__ wA, const us* __restrict__ wB,
    const us* __restrict__ cA, const us* __restrict__ cB,
    const float* __restrict__ dbA, const float* __restrict__ dbB,
    const float* __restrict__ cbA, const float* __restrict__ cbB,
    us* __restrict__ gA_out, us* __restrict__ gB_out,
    int Lin, int ntB)
{
    __shared__ __align__(16) float xs[4 * 32 * CC];   // 4 input strips fp32
    __shared__ __align__(16) float ms[2 * 32 * CC];   // mid strips {0,2D} fp32
    __shared__ __align__(16) us  scr[4 * 16 * CC];    // wave g scratch

    const int tid = threadIdx.x, lane = tid & 63, wv = tid >> 6;
    const int b = blockIdx.x / ntB, T0 = (blockIdx.x % ntB) * 32;
    const float* src = cur + (size_t)b * LL0 * CC;
    const int s = lane & 15, q = lane >> 4;
    us* myscr = scr + wv * (16 * CC);
    const int LoutA = Lin - D, Lout2 = Lin - 3 * D;

    #pragma unroll
    for (int p = 0; p < 8; ++p) {
        const int row = p * 16 + (tid >> 4);
        const int st = row >> 5, r = row & 31;
        const int h4 = (tid & 15) * 4;
        int gt = T0 + st * D + r; if (gt > Lin - 1) gt = Lin - 1;
        *(f32x4*)(xs + st * (32 * CC) + sws(r, h4)) =
            *(const f32x4*)(src + (size_t)gt * CC + h4);
    }
    __syncthreads();

    // ---- A phase: mid strips m=0 (waves 0,1), m=1 (waves 2,3) ----
    {
        const int m = wv >> 1, rA = (wv & 1) * 16 + s;
        const int tA = T0 + m * 2 * D + rA;
        const float* x0 = xs + (2 * m) * (32 * CC);
        const float* x1 = xs + (2 * m + 1) * (32 * CC);
        bf16x8 af0, af1, af2, af3;
        {
            f32x4 a = *(const f32x4*)(x0 + sws(rA, q * 8));
            f32x4 bb = *(const f32x4*)(x0 + sws(rA, q * 8 + 4));
            af0 = (bf16x8){(short)f2bf(a[0]),(short)f2bf(a[1]),(short)f2bf(a[2]),(short)f2bf(a[3]),
                           (short)f2bf(bb[0]),(short)f2bf(bb[1]),(short)f2bf(bb[2]),(short)f2bf(bb[3])};
            a = *(const f32x4*)(x0 + sws(rA, 32 + q * 8));
            bb = *(const f32x4*)(x0 + sws(rA, 36 + q * 8));
            af1 = (bf16x8){(short)f2bf(a[0]),(short)f2bf(a[1]),(short)f2bf(a[2]),(short)f2bf(a[3]),
                           (short)f2bf(bb[0]),(short)f2bf(bb[1]),(short)f2bf(bb[2]),(short)f2bf(bb[3])};
            a = *(const f32x4*)(x1 + sws(rA, q * 8));
            bb = *(const f32x4*)(x1 + sws(rA, q * 8 + 4));
            af2 = (bf16x8){(short)f2bf(a[0]),(short)f2bf(a[1]),(short)f2bf(a[2]),(short)f2bf(a[3]),
                           (short)f2bf(bb[0]),(short)f2bf(bb[1]),(short)f2bf(bb[2]),(short)f2bf(bb[3])};
            a = *(const f32x4*)(x1 + sws(rA, 32 + q * 8));
            bb = *(const f32x4*)(x1 + sws(rA, 36 + q * 8));
            af3 = (bf16x8){(short)f2bf(a[0]),(short)f2bf(a[1]),(short)f2bf(a[2]),(short)f2bf(a[3]),
                           (short)f2bf(bb[0]),(short)f2bf(bb[1]),(short)f2bf(bb[2]),(short)f2bf(bb[3])};
        }
        #pragma unroll
        for (int n = 0; n < 4; ++n) {
            const int o0 = n * 16 + q * 4;
            f32x4 acc = *(const f32x4*)(dbA + o0);
            const us* wr = wA + (n * 16 + s) * 128 + q * 8;
            acc = __builtin_amdgcn_mfma_f32_16x16x32_bf16(*(const bf16x8*)(wr),      af0, acc, 0, 0, 0);
            acc = __builtin_amdgcn_mfma_f32_16x16x32_bf16(*(const bf16x8*)(wr + 32), af1, acc, 0, 0, 0);
            acc = __builtin_amdgcn_mfma_f32_16x16x32_bf16(*(const bf16x8*)(wr + 64), af2, acc, 0, 0, 0);
            acc = __builtin_amdgcn_mfma_f32_16x16x32_bf16(*(const bf16x8*)(wr + 96), af3, acc, 0, 0, 0);
            #pragma unroll
            for (int r = 0; r < 4; ++r) acc[r] = acc[r] > 0.f ? acc[r] : 0.f;
            *(uint2*)(myscr + scb(s, n * 2 + (q >> 1)) + (q & 1) * 4) = pk4(acc);
        }
        // gA window store: strip0 owns t<ntB*32; strip1 covers the tail
        {
            const int wbA = LoutA - SKIPN;
            const bool own = (m == 0) || (tA >= ntB * 32);
            if (own && tA >= wbA && tA < LoutA) {
                us* gr = gA_out + ((size_t)b * SKIPN + (tA - wbA)) * CC;
                #pragma unroll
                for (int h = 0; h < 2; ++h) {
                    const int ck = q * 2 + h;
                    *(bf16x8*)(gr + ck * 8) = *(const bf16x8*)(myscr + scb(s, ck));
                }
            }
        }
        // 1x1 A + residual (tap-1: input[tA + D] = x1) -> ms[m]
        bf16x8 g0 = *(const bf16x8*)(myscr + scb(s, q));
        bf16x8 g1 = *(const bf16x8*)(myscr + scb(s, 4 + q));
        #pragma unroll
        for (int n = 0; n < 4; ++n) {
            const int o0 = n * 16 + q * 4;
            f32x4 r = *(const f32x4*)(cbA + o0);
            const us* wr = cA + (n * 16 + s) * CC + q * 8;
            r = __builtin_amdgcn_mfma_f32_16x16x32_bf16(*(const bf16x8*)(wr),      g0, r, 0, 0, 0);
            r = __builtin_amdgcn_mfma_f32_16x16x32_bf16(*(const bf16x8*)(wr + 32), g1, r, 0, 0, 0);
            r += *(const f32x4*)(x1 + sws(rA, o0));
            *(f32x4*)(ms + m * (32 * CC) + sws(rA, o0)) = r;
        }
    }
    __syncthreads();

    // ---- B phase: out rows T0..T0+32 (waves 2,3 duplicate, stores gated) ----
    {
        const int rB = (wv & 1) * 16 + s;
        const int tB = T0 + rB;
        const bool lead = wv < 2;
        const float* m0 = ms;
        const float* m1 = ms + 32 * CC;
        bf16x8 af0, af1, af2, af3;
        {
            f32x4 a = *(const f32x4*)(m0 + sws(rB, q * 8));
            f32x4 bb = *(const f32x4*)(m0 + sws(rB, q * 8 + 4));
            af0 = (bf16x8){(short)f2bf(a[0]),(short)f2bf(a[1]),(short)f2bf(a[2]),(short)f2bf(a[3]),
                           (short)f2bf(bb[0]),(short)f2bf(bb[1]),(short)f2bf(bb[2]),(short)f2bf(bb[3])};
            a = *(const f32x4*)(m0 + sws(rB, 32 + q * 8));
            bb = *(const f32x4*)(m0 + sws(rB, 36 + q * 8));
            af1 = (bf16x8){(short)f2bf(a[0]),(short)f2bf(a[1]),(short)f2bf(a[2]),(short)f2bf(a[3]),
                           (short)f2bf(bb[0]),(short)f2bf(bb[1]),(short)f2bf(bb[2]),(short)f2bf(bb[3])};
            a = *(const f32x4*)(m1 + sws(rB, q * 8));
            bb = *(const f32x4*)(m1 + sws(rB, q * 8 + 4));
            af2 = (bf16x8){(short)f2bf(a[0]),(short)f2bf(a[1]),(short)f2bf(a[2]),(short)f2bf(a[3]),
                           (short)f2bf(bb[0]),(short)f2bf(bb[1]),(short)f2bf(bb[2]),(short)f2bf(bb[3])};
            a = *(const f32x4*)(m1 + sws(rB, 32 + q * 8));
            bb = *(const f32x4*)(m1 + sws(rB, 36 + q * 8));
            af3 = (bf16x8){(short)f2bf(a[0]),(short)f2bf(a[1]),(short)f2bf(a[2]),(short)f2bf(a[3]),
                           (short)f2bf(bb[0]),(short)f2bf(bb[1]),(short)f2bf(bb[2]),(short)f2bf(bb[3])};
        }
        #pragma unroll
        for (int n = 0; n < 4; ++n) {
            const int o0 = n * 16 + q * 4;
            f32x4 acc = *(const f32x4*)(dbB + o0);
            const us* wr = wB + (n * 16 + s) * 128 + q * 8;
            acc = __builtin_amdgcn_mfma_f32_16x16x32_bf16(*(const bf16x8*)(wr),      af0, acc, 0, 0, 0);
            acc = __builtin_amdgcn_mfma_f32_16x16x32_bf16(*(const bf16x8*)(wr + 32), af1, acc, 0, 0, 0);
            acc = __builtin_amdgcn_mfma_f32_16x16x32_bf16(*(const bf16x8*)(wr + 64), af2, acc, 0, 0, 0);
            acc = __builtin_amdgcn_mfma_f32_16x16x32_bf16(*(const bf16x8*)(wr + 96), af3, acc, 0, 0, 0);
            #pragma unroll
            for (int r = 0; r < 4; ++r) acc[r] = acc[r] > 0.f ? acc[r] : 0.f;
            *(uint2*)(myscr + scb(s, n * 2 + (q >> 1)) + (q & 1) * 4) = pk4(acc);
        }
        {
            const int wbB = Lout2 - SKIPN;
            if (lead && tB >= wbB && tB < Lout2) {
                us* gr = gB_out + ((size_t)b * SKIPN + (tB - wbB)) * CC;
                #pragma unroll
                for (int h = 0; h < 2; ++h) {
                    const int ck = q * 2 + h;
                    *(bf16x8*)(gr + ck * 8) = *(const bf16x8*)(myscr + scb(s, ck));
                }
            }
        }
        // 1x1 B + residual (tap-1: A_out[tB + 2D] = m1)
        bf16x8 g0 = *(const bf16x8*)(myscr + scb(s, q));
        bf16x8 g1 = *(const bf16x8*)(myscr + scb(s, 4 + q));
        float* dst = nxt + (size_t)b * LL0 * CC;
        #pragma unroll
        for (int n = 0; n < 4; ++n) {
            const int o0 = n * 16 + q * 4;
            f32x4 r = *(const f32x4*)(cbB + o0);
            const us* wr = cB + (n * 16 + s) * CC + q * 8;
            r = __builtin_amdgcn_mfma_f32_16x16x32_bf16(*(const bf16x8*)(wr),      g0, r, 0, 0, 0);
            r = __builtin_amdgcn_mfma_f32_16x16x32_bf16(*(const bf16x8*)(wr + 32), g1, r, 0, 0, 0);
            r += *(const f32x4*)(m1 + sws(rB, o0));
            if (lead && tB < Lout2)
                *(f32x4*)(dst + (size_t)tB * CC + o0) = r;
        }
    }
}

// ================= ONE skip kernel for all 40 blocks (256 threads) ============
__global__ __launch_bounds__(256) void skip_all_kernel(
    const us* __restrict__ g_all, const us* __restrict__ swb,
    const float* __restrict__ skip_b, float* __restrict__ out)
{
    const int ntile = SKIPN / 64;   // 64 tiles of 64 rows
    const int tid = threadIdx.x, lane = tid & 63, wv = tid >> 6;
    int id = blockIdx.x;
    const int tt = id % ntile; id /= ntile;
    const int b  = id % BB;    id /= BB;
    const int blk = id;

    const us* g  = g_all + ((size_t)blk * BB + b) * SKIPN * CC;
    const us* sw = swb + (size_t)blk * SCC * CC;
    const float* sb = skip_b + blk * SCC;
    float* op = out + ((size_t)blk * BB + b) * SCC * SKIPN;

    const int trow = tt * 64 + wv * 16 + (lane & 15);
    bf16x8 a[2];
    a[0] = *(const bf16x8*)(g + (size_t)trow * CC + (lane >> 4) * 8);
    a[1] = *(const bf16x8*)(g + (size_t)trow * CC + 32 + (lane >> 4) * 8);

    const int tstore = tt * 64 + wv * 16 + ((lane >> 4) << 2);
    #pragma unroll 4
    for (int n = 0; n < 16; ++n) {
        const int sc = n * 16 + (lane & 15);
        const float bias = sb[sc];
        f32x4 acc = (f32x4){bias, bias, bias, bias};
        const us* wrow = sw + sc * CC + (lane >> 4) * 8;
        acc = __builtin_amdgcn_mfma_f32_16x16x32_bf16(a[0], *(const bf16x8*)(wrow), acc, 0, 0, 0);
        acc = __builtin_amdgcn_mfma_f32_16x16x32_bf16(a[1], *(const bf16x8*)(wrow + 32), acc, 0, 0, 0);
        *(float4*)(op + (size_t)sc * SKIPN + tstore) = (float4){acc[0], acc[1], acc[2], acc[3]};
    }
}

extern "C" void kernel_launch(void* const* d_in, const int* in_sizes, int n_in,
                              void* d_out, int out_size, void* d_ws, size_t ws_size,
                              hipStream_t stream)
{
    const float* x      = (const float*)d_in[0];
    const float* dc_w   = (const float*)d_in[1];
    const float* dc_b   = (const float*)d_in[2];
    const float* conv_w = (const float*)d_in[3];
    const float* conv_b = (const float*)d_in[4];
    const float* skip_w = (const float*)d_in[5];
    const float* skip_b = (const float*)d_in[6];
    float* out = (float*)d_out;

    char* ws = (char*)d_ws;
    float* bufA = (float*)ws;  ws += (size_t)BB * LL0 * CC * 4;
    float* bufB = (float*)ws;  ws += (size_t)BB * LL0 * CC * 4;
    us* g_all = (us*)ws;       ws += (size_t)NBLK * BB * SKIPN * CC * 2;
    us* wcat = (us*)ws;        ws += (size_t)NBLK * CC * 128 * 2;
    us* cwb  = (us*)ws;        ws += (size_t)NBLK * CC * CC * 2;
    us* swb  = (us*)ws;        ws += (size_t)NBLK * SCC * CC * 2;

    prep_kernel<<<1536, 256, 0, stream>>>(x, bufA, dc_w, conv_w, skip_w, wcat, cwb, swb);

    float* bufs[2] = {bufA, bufB};
    const size_t GSZ = (size_t)BB * SKIPN * CC;
    int Lc = LL0, blk = 0, qq = 0;
    for (int st = 0; st < 4; ++st) {
        {   // fused d=1..32 (blocks blk..blk+5)
            const int Lout = Lc - 63;
            const int nt = (Lout + 95) / 96;
            fused6_kernel<<<dim3(BB * nt), 512, 0, stream>>>(
                bufs[qq & 1], bufs[(qq + 1) & 1], wcat, cwb, dc_b, conv_b,
                g_all, blk, Lc, nt);
            blk += 6; Lc = Lout; ++qq;
        }
        for (int pi = 0; pi < 2; ++pi) {  // pair<64> then pair<256>
            const int D = pi == 0 ? 64 : 256;
            const int Lout2 = Lc - 3 * D;
            const int nt = (Lout2 + 31) / 32;
            if (D == 64)
                pair_kernel<64><<<dim3(BB * nt), 256, 0, stream>>>(
                    bufs[qq & 1], bufs[(qq + 1) & 1],
                    wcat + (size_t)blk * CC * 128, wcat + (size_t)(blk + 1) * CC * 128,
                    cwb + (size_t)blk * CC * CC, cwb + (size_t)(blk + 1) * CC * CC,
                    dc_b + blk * CC, dc_b + (blk + 1) * CC,
                    conv_b + blk * CC, conv_b + (blk + 1) * CC,
                    g_all + (size_t)blk * GSZ, g_all + (size_t)(blk + 1) * GSZ,
                    Lc, nt);
            else
                pair_kernel<256><<<dim3(BB * nt), 256, 0, stream>>>(
                    bufs[qq & 1], bufs[(qq + 1) & 1],
                    wcat + (size_t)blk * CC * 128, wcat + (size_t)(blk + 1) * CC * 128,
                    cwb + (size_t)blk * CC * CC, cwb + (size_t)(blk + 1) * CC * CC,
                    dc_b + blk * CC, dc_b + (blk + 1) * CC,
                    conv_b + blk * CC, conv_b + (blk + 1) * CC,
                    g_all + (size_t)blk * GSZ, g_all + (size_t)(blk + 1) * GSZ,
                    Lc, nt);
            blk += 2; Lc = Lout2; ++qq;
        }
    }

    skip_all_kernel<<<dim3(NBLK * BB * (SKIPN / 64)), 256, 0, stream>>>(
        g_all, swb, skip_b, out);
}

// Round 13
// 716.239 us; speedup vs baseline: 1.4174x; 1.1653x over previous
//
#include <hip/hip_runtime.h>

// WaveNet residual stack, MFMA bf16. Champion structure (R5) + capacity fixes:
//   prep (transpose+weights merged) + per stack { fused6 (d=1..32, 2-barrier
//   bf16-shadow) + 4 singles (d=64..512, R5-proven) } + tiny skip tail.
// Skip GEMMs piggyback on later chain launches (fused cap 1 -> 468<=512
// co-resident; singles cap 3 -> 1780<=1792). Stream fp32 [b][t][c].

#define CC    64
#define SCC   256
#define BB    4
#define LL0   8192
#define NBLK  40
#define SKIPN 4096
#define TTC   32

typedef __attribute__((ext_vector_type(8))) short bf16x8;
typedef __attribute__((ext_vector_type(4))) float f32x4;
typedef unsigned short us;

__device__ __forceinline__ us f2bf(float f) {
    union { float f; unsigned u; } v; v.f = f;
    return (us)((v.u + 0x7FFF + ((v.u >> 16) & 1)) >> 16);
}
__device__ __forceinline__ unsigned pk2(float a, float b) {
    return (unsigned)f2bf(a) | ((unsigned)f2bf(b) << 16);
}
__device__ __forceinline__ uint2 pk4(f32x4 v) {
    return (uint2){pk2(v[0], v[1]), pk2(v[2], v[3])};
}
// fp32 [row][64] LDS word index, 32B-chunk XOR swizzle
__device__ __forceinline__ int sws(int r, int c) {
    return (r << 6) + ((((c >> 3) ^ r) & 7) << 3) + (c & 7);
}
// bf16 [row][64] LDS elem index, 16B-chunk XOR swizzle
__device__ __forceinline__ int swh(int r, int c) {
    return (r << 6) + ((((c >> 3) ^ r) & 7) << 3) + (c & 7);
}
// bf16 [row][128] LDS elem index, XOR on low 3 chunk bits
__device__ __forceinline__ int swx(int r, int k) {
    int ch = k >> 3; ch = (ch & 8) | ((ch ^ r) & 7);
    return (r << 7) + (ch << 3) + (k & 7);
}
// wave-private bf16 scratch [16 rows][64 c], 16B-chunk XOR swizzle
__device__ __forceinline__ int scb(int s, int chunk) {
    return (s << 6) + (((chunk ^ (s & 7)) & 7) << 3);
}

// ---- merged prep: x transpose [b][c][t]->[b][t][c] + weight bf16 casts ----
__global__ __launch_bounds__(256) void prep_kernel(
    const float* __restrict__ x, float* __restrict__ xt_out,
    const float* __restrict__ dc_w, const float* __restrict__ conv_w,
    const float* __restrict__ skip_w,
    us* __restrict__ wcat, us* __restrict__ cwb, us* __restrict__ swb)
{
    if (blockIdx.x < 512) {
        __shared__ float tile[64][65];
        const int b = blockIdx.x >> 7, t0 = (blockIdx.x & 127) * 64;
        const int tid = threadIdx.x;
        #pragma unroll
        for (int p = 0; p < 4; ++p) {
            const int c = p * 16 + (tid >> 4), j = tid & 15;
            const float4 v = *(const float4*)(x + ((size_t)b * CC + c) * LL0 + t0 + j * 4);
            tile[c][j*4+0]=v.x; tile[c][j*4+1]=v.y; tile[c][j*4+2]=v.z; tile[c][j*4+3]=v.w;
        }
        __syncthreads();
        #pragma unroll
        for (int p = 0; p < 4; ++p) {
            const int r = p * 16 + (tid >> 4), h = tid & 15;
            float4 v = {tile[h*4+0][r], tile[h*4+1][r], tile[h*4+2][r], tile[h*4+3][r]};
            *(float4*)(xt_out + ((size_t)b * LL0 + t0 + r) * CC + h * 4) = v;
        }
        return;
    }
    const int n_sw = NBLK * SCC * CC, n_cw = NBLK * CC * CC, n_wc = NBLK * CC * 128;
    for (int idx = (blockIdx.x - 512) * blockDim.x + threadIdx.x; idx < n_sw;
         idx += 1024 * blockDim.x) {
        swb[idx] = f2bf(skip_w[idx]);
        if (idx < n_cw) cwb[idx] = f2bf(conv_w[idx]);
        if (idx < n_wc) {
            const int i = idx >> 13, o = (idx >> 7) & 63, kk = idx & 127;
            wcat[idx] = f2bf(dc_w[(((i * CC + o) * CC) + (kk & 63)) * 2 + (kk >> 6)]);
        }
    }
}

// ---- skip GEMM body; NW waves, tile = NW*16 time rows ----
template<int NW>
__device__ __forceinline__ void skip_body(
    int e, int blk0,
    const us* __restrict__ g_all, const us* __restrict__ swb,
    const float* __restrict__ skip_b, float* __restrict__ out)
{
    constexpr int ROWS = NW * 16;
    constexpr int TPB = (SKIPN / ROWS) * BB;
    const int tid = threadIdx.x, lane = tid & 63, wv = tid >> 6;
    const int j = blk0 + e / TPB;
    const int id = e % TPB;
    const int tt = id % (SKIPN / ROWS);
    const int b  = id / (SKIPN / ROWS);
    const us* g  = g_all + ((size_t)j * BB + b) * SKIPN * CC;
    const us* sw = swb + (size_t)j * SCC * CC;
    const float* sb = skip_b + j * SCC;
    float* op = out + ((size_t)j * BB + b) * SCC * SKIPN;

    const int trow = tt * ROWS + wv * 16 + (lane & 15);
    bf16x8 a[2];
    a[0] = *(const bf16x8*)(g + (size_t)trow * CC + (lane >> 4) * 8);
    a[1] = *(const bf16x8*)(g + (size_t)trow * CC + 32 + (lane >> 4) * 8);
    const int tstore = tt * ROWS + wv * 16 + ((lane >> 4) << 2);
    #pragma unroll 4
    for (int n = 0; n < 16; ++n) {
        const int sc = n * 16 + (lane & 15);
        const float bias = sb[sc];
        f32x4 acc = (f32x4){bias, bias, bias, bias};
        const us* wrow = sw + sc * CC + (lane >> 4) * 8;
        acc = __builtin_amdgcn_mfma_f32_16x16x32_bf16(a[0], *(const bf16x8*)(wrow), acc, 0, 0, 0);
        acc = __builtin_amdgcn_mfma_f32_16x16x32_bf16(a[1], *(const bf16x8*)(wrow + 32), acc, 0, 0, 0);
        *(float4*)(op + (size_t)sc * SKIPN + tstore) = (float4){acc[0], acc[1], acc[2], acc[3]};
    }
}

// ================= fused d=1..32 kernel (512 threads, 2 barriers/block) =======
// sm fp32 40KB + smb bf16 20KB + scr 16KB = 76KB -> 2 WGs/CU; 340+128 <= 512.
__global__ __launch_bounds__(512) void fused6_kernel(
    const float* __restrict__ cur, float* __restrict__ nxt,
    const us* __restrict__ wcat_all, const us* __restrict__ cwb_all,
    const float* __restrict__ db_all, const float* __restrict__ cb_all,
    us* __restrict__ g_all, int blk0, int Lin, int ntiles,
    const us* __restrict__ swb, const float* __restrict__ skip_b,
    float* __restrict__ out, int pb0)
{
    const int wg = blockIdx.x, chain = BB * ntiles;
    if (wg >= chain) { skip_body<8>(wg - chain, pb0, g_all, swb, skip_b, out); return; }

    constexpr int TOUT = 96, R0 = 159, RCAP = 160;
    __shared__ __align__(16) float sm[RCAP * CC];
    __shared__ __align__(16) us  smb[RCAP * CC];
    __shared__ __align__(16) us  scr[8 * 16 * CC];

    const int tid = threadIdx.x, lane = tid & 63, wv = tid >> 6;
    const int b = wg / ntiles, t0 = (wg % ntiles) * TOUT;
    const float* src = cur + (size_t)b * LL0 * CC;
    const int s = lane & 15, q = lane >> 4;
    us* myscr = scr + wv * (16 * CC);

    for (int base = 0; base < R0; base += 32) {
        const int row = base + (tid >> 4);
        const int h4 = (tid & 15) * 4;
        if (row < R0) {
            int gt = t0 + row; if (gt > Lin - 1) gt = Lin - 1;
            f32x4 v = *(const f32x4*)(src + (size_t)gt * CC + h4);
            *(f32x4*)(sm + sws(row, h4)) = v;
            *(uint2*)(smb + swh(row, h4)) = pk4(v);
        }
    }
    __syncthreads();

    int Rcur = R0, Lj = Lin;
    for (int j = 0; j < 6; ++j) {
        const int d = 1 << j;
        const int Rn = Rcur - d;
        Lj -= d;
        const us* wj = wcat_all + (size_t)(blk0 + j) * CC * 128;
        const us* cj = cwb_all + (size_t)(blk0 + j) * CC * CC;
        const float* dbj = db_all + (blk0 + j) * CC;
        const float* cbj = cb_all + (blk0 + j) * CC;
        const int wbase = Lj - SKIPN;
        us* gdst = g_all + ((size_t)(blk0 + j) * BB + b) * SKIPN * CC;

        f32x4 r2[2][4];
        #pragma unroll
        for (int fi = 0; fi < 2; ++fi) {
            const int fg = wv + fi * 8;
            if (fg * 16 < Rn) {
                const int t = fg * 16 + s;
                const int tc = t > Rn - 1 ? Rn - 1 : t;
                bf16x8 af0 = *(const bf16x8*)(smb + swh(tc,     q * 8));
                bf16x8 af1 = *(const bf16x8*)(smb + swh(tc,     32 + q * 8));
                bf16x8 af2 = *(const bf16x8*)(smb + swh(tc + d, q * 8));
                bf16x8 af3 = *(const bf16x8*)(smb + swh(tc + d, 32 + q * 8));
                #pragma unroll
                for (int n = 0; n < 4; ++n) {
                    const int o0 = n * 16 + q * 4;
                    f32x4 acc = *(const f32x4*)(dbj + o0);
                    const us* wr = wj + (n * 16 + s) * 128 + q * 8;
                    acc = __builtin_amdgcn_mfma_f32_16x16x32_bf16(*(const bf16x8*)(wr),      af0, acc, 0, 0, 0);
                    acc = __builtin_amdgcn_mfma_f32_16x16x32_bf16(*(const bf16x8*)(wr + 32), af1, acc, 0, 0, 0);
                    acc = __builtin_amdgcn_mfma_f32_16x16x32_bf16(*(const bf16x8*)(wr + 64), af2, acc, 0, 0, 0);
                    acc = __builtin_amdgcn_mfma_f32_16x16x32_bf16(*(const bf16x8*)(wr + 96), af3, acc, 0, 0, 0);
                    #pragma unroll
                    for (int r = 0; r < 4; ++r) acc[r] = acc[r] > 0.f ? acc[r] : 0.f;
                    *(uint2*)(myscr + scb(s, n * 2 + (q >> 1)) + (q & 1) * 4) = pk4(acc);
                }
                bf16x8 g0 = *(const bf16x8*)(myscr + scb(s, q));
                bf16x8 g1 = *(const bf16x8*)(myscr + scb(s, 4 + q));
                {
                    const int gt = t0 + t;
                    if (t < Rn && gt >= wbase && gt < Lj) {
                        us* gr = gdst + (size_t)(gt - wbase) * CC;
                        #pragma unroll
                        for (int h = 0; h < 2; ++h) {
                            const int ck = q * 2 + h;
                            *(bf16x8*)(gr + ck * 8) = *(const bf16x8*)(myscr + scb(s, ck));
                        }
                    }
                }
                #pragma unroll
                for (int n = 0; n < 4; ++n) {
                    const int o0 = n * 16 + q * 4;
                    f32x4 r = *(const f32x4*)(cbj + o0);
                    const us* wr = cj + (n * 16 + s) * CC + q * 8;
                    r = __builtin_amdgcn_mfma_f32_16x16x32_bf16(*(const bf16x8*)(wr),      g0, r, 0, 0, 0);
                    r = __builtin_amdgcn_mfma_f32_16x16x32_bf16(*(const bf16x8*)(wr + 32), g1, r, 0, 0, 0);
                    r += *(const f32x4*)(sm + sws(tc + d, o0));
                    r2[fi][n] = r;
                }
            }
        }
        __syncthreads();
        #pragma unroll
        for (int fi = 0; fi < 2; ++fi) {
            const int fg = wv + fi * 8;
            const int t = fg * 16 + s;
            if (t < Rn) {
                #pragma unroll
                for (int n = 0; n < 4; ++n) {
                    const int o0 = n * 16 + q * 4;
                    *(f32x4*)(sm + sws(t, o0)) = r2[fi][n];
                    *(uint2*)(smb + swh(t, o0)) = pk4(r2[fi][n]);
                }
            }
        }
        __syncthreads();
        Rcur = Rn;
    }

    float* dst = nxt + (size_t)b * LL0 * CC;
    for (int base = 0; base < TOUT; base += 32) {
        const int row = base + (tid >> 4);
        const int h4 = (tid & 15) * 4;
        const int gt = t0 + row;
        if (row < TOUT && gt < Lj)
            *(float4*)(dst + (size_t)gt * CC + h4) = *(const float4*)(sm + sws(row, h4));
    }
}

// ================= single-block kernel (R5-proven: 256 thr, TTC=32) ===========
// xt 8K + gs 4K + x1f 8.4K = 20.6KB -> 7 WGs/CU; 1012 chain + 768 skip <= 1792.
__global__ __launch_bounds__(256) void block_kernel(
    const float* __restrict__ cur, float* __restrict__ nxt,
    const us* __restrict__ wcat, const us* __restrict__ cwb,
    const float* __restrict__ db, const float* __restrict__ cb,
    us* __restrict__ g_out,
    int d, int Lin, int Lout, int ntiles,
    const us* __restrict__ g_all, const us* __restrict__ swb,
    const float* __restrict__ skip_b, float* __restrict__ out, int pb0)
{
    const int wg = blockIdx.x, chain = BB * ntiles;
    if (wg >= chain) { skip_body<4>(wg - chain, pb0, g_all, swb, skip_b, out); return; }

    __shared__ __align__(16) us xt[TTC * 128];
    __shared__ __align__(16) us gs[TTC * CC];
    __shared__ float x1f[CC][TTC + 1];

    const int tid = threadIdx.x, lane = tid & 63, wv = tid >> 6;
    const int b = wg / ntiles, t0 = (wg % ntiles) * TTC;
    const float* src = cur + (size_t)b * LL0 * CC;

    // ---- stage both taps + fp32 x1 stash ----
    #pragma unroll
    for (int p = 0; p < 2; ++p) {
        const int row = p * 16 + (tid >> 4);
        const int h = tid & 15;
        int ta = t0 + row;     if (ta > Lin - 1) ta = Lin - 1;
        int tb = t0 + row + d; if (tb > Lin - 1) tb = Lin - 1;
        const float4 v0 = *(const float4*)(src + (size_t)ta * CC + h * 4);
        const float4 v1 = *(const float4*)(src + (size_t)tb * CC + h * 4);
        uint2 p0, p1;
        p0.x = pk2(v0.x, v0.y); p0.y = pk2(v0.z, v0.w);
        p1.x = pk2(v1.x, v1.y); p1.y = pk2(v1.z, v1.w);
        *(uint2*)(xt + swx(row, h * 4)) = p0;
        *(uint2*)(xt + swx(row, 64 + h * 4)) = p1;
        x1f[h * 4 + 0][row] = v1.x;
        x1f[h * 4 + 1][row] = v1.y;
        x1f[h * 4 + 2][row] = v1.z;
        x1f[h * 4 + 3][row] = v1.w;
    }
    __syncthreads();

    const int rf = wv >> 1, oh = wv & 1;
    const int row = rf * 16 + (lane & 15);

    // ---- GEMM1 + relu -> gs ----
    bf16x8 a1[4];
    #pragma unroll
    for (int ks = 0; ks < 4; ++ks)
        a1[ks] = *(const bf16x8*)(xt + swx(row, ks * 32 + (lane >> 4) * 8));
    f32x4 acc[2];
    #pragma unroll
    for (int n = 0; n < 2; ++n) {
        const int o = oh * 32 + n * 16 + (lane & 15);
        const float bias = db[o];
        acc[n] = (f32x4){bias, bias, bias, bias};
        const us* wrow = wcat + o * 128 + (lane >> 4) * 8;
        #pragma unroll
        for (int ks = 0; ks < 4; ++ks)
            acc[n] = __builtin_amdgcn_mfma_f32_16x16x32_bf16(
                a1[ks], *(const bf16x8*)(wrow + ks * 32), acc[n], 0, 0, 0);
    }
    const int wr = rf * 16 + ((lane >> 4) << 2);
    #pragma unroll
    for (int n = 0; n < 2; ++n) {
        const int o = oh * 32 + n * 16 + (lane & 15);
        #pragma unroll
        for (int r = 0; r < 4; ++r) {
            float g = acc[n][r]; g = g > 0.f ? g : 0.f;
            gs[swh(wr + r, o)] = f2bf(g);
        }
    }
    __syncthreads();

    // ---- GEMM2 + residual + OUT store ----
    bf16x8 a2[2];
    #pragma unroll
    for (int ks = 0; ks < 2; ++ks)
        a2[ks] = *(const bf16x8*)(gs + swh(row, ks * 32 + (lane >> 4) * 8));
    {
        const int tloc = wr;
        const int t = t0 + tloc;
        #pragma unroll
        for (int n = 0; n < 2; ++n) {
            const int o = oh * 32 + n * 16 + (lane & 15);
            const float bias = cb[o];
            f32x4 racc = (f32x4){bias, bias, bias, bias};
            const us* wrow = cwb + o * CC + (lane >> 4) * 8;
            racc = __builtin_amdgcn_mfma_f32_16x16x32_bf16(a2[0], *(const bf16x8*)(wrow), racc, 0, 0, 0);
            racc = __builtin_amdgcn_mfma_f32_16x16x32_bf16(a2[1], *(const bf16x8*)(wrow + 32), racc, 0, 0, 0);
            float* outp = nxt + (size_t)b * LL0 * CC + (size_t)t * CC + o;
            #pragma unroll
            for (int r = 0; r < 4; ++r)
                if (t + r < Lout) outp[(size_t)r * CC] = racc[r] + x1f[o][tloc + r];
        }
    }

    // ---- g window store ----
    {
        const int row2 = tid >> 3, ch8 = tid & 7;
        const int gt = t0 + row2;
        const int wbase = Lout - SKIPN;
        if (gt >= wbase && gt < Lout)
            *(bf16x8*)(g_out + ((size_t)b * SKIPN + (gt - wbase)) * CC + ch8 * 8) =
                *(const bf16x8*)(gs + swh(row2, ch8 * 8));
    }
}

__global__ __launch_bounds__(256) void skip_kernel(
    const us* __restrict__ g_all, const us* __restrict__ swb,
    const float* __restrict__ skip_b, float* __restrict__ out, int blk0)
{
    skip_body<4>(blockIdx.x, blk0, g_all, swb, skip_b, out);
}

extern "C" void kernel_launch(void* const* d_in, const int* in_sizes, int n_in,
                              void* d_out, int out_size, void* d_ws, size_t ws_size,
                              hipStream_t stream)
{
    const float* x      = (const float*)d_in[0];
    const float* dc_w   = (const float*)d_in[1];
    const float* dc_b   = (const float*)d_in[2];
    const float* conv_w = (const float*)d_in[3];
    const float* conv_b = (const float*)d_in[4];
    const float* skip_w = (const float*)d_in[5];
    const float* skip_b = (const float*)d_in[6];
    float* out = (float*)d_out;

    char* ws = (char*)d_ws;
    float* bufA = (float*)ws;  ws += (size_t)BB * LL0 * CC * 4;
    float* bufB = (float*)ws;  ws += (size_t)BB * LL0 * CC * 4;
    us* g_all = (us*)ws;       ws += (size_t)NBLK * BB * SKIPN * CC * 2;
    us* wcat = (us*)ws;        ws += (size_t)NBLK * CC * 128 * 2;
    us* cwb  = (us*)ws;        ws += (size_t)NBLK * CC * CC * 2;
    us* swb  = (us*)ws;        ws += (size_t)NBLK * SCC * CC * 2;

    prep_kernel<<<1536, 256, 0, stream>>>(x, bufA, dc_w, conv_w, skip_w, wcat, cwb, swb);

    float* bufs[2] = {bufA, bufB};
    const size_t GSZ = (size_t)BB * SKIPN * CC;
    int Lc = LL0, blk = 0, qq = 0, produced = 0, skipped = 0;
    for (int st = 0; st < 4; ++st) {
        {   // fused d=1..32 (blocks blk..blk+5); piggyback cap 1 (co-residency)
            const int Lout = Lc - 63;
            const int nt = (Lout + 95) / 96;
            int cap = produced - skipped; if (cap > 1) cap = 1;
            fused6_kernel<<<dim3(BB * nt + cap * 128), 512, 0, stream>>>(
                bufs[qq & 1], bufs[(qq + 1) & 1], wcat, cwb, dc_b, conv_b,
                g_all, blk, Lc, nt, swb, skip_b, out, skipped);
            skipped += cap; produced += 6; blk += 6; Lc = Lout; ++qq;
        }
        for (int dl = 6; dl < 10; ++dl) {   // d = 64..512 singles; cap 3
            const int d = 1 << dl;
            const int Lout = Lc - d;
            const int nt = (Lout + TTC - 1) / TTC;
            int cap = produced - skipped; if (cap > 3) cap = 3;
            block_kernel<<<dim3(BB * nt + cap * 256), 256, 0, stream>>>(
                bufs[qq & 1], bufs[(qq + 1) & 1],
                wcat + (size_t)blk * CC * 128, cwb + (size_t)blk * CC * CC,
                dc_b + blk * CC, conv_b + blk * CC,
                g_all + (size_t)blk * GSZ,
                d, Lc, Lout, nt, g_all, swb, skip_b, out, skipped);
            skipped += cap; produced += 1; blk += 1; Lc = Lout; ++qq;
        }
    }
    const int rem = NBLK - skipped;
    if (rem > 0)
        skip_kernel<<<dim3(rem * 256), 256, 0, stream>>>(g_all, swb, skip_b, out, skipped);
}